// Round 3
// baseline (514.426 us; speedup 1.0000x reference)
//
#include <hip/hip_runtime.h>
#include <hip/hip_bf16.h>
#include <cmath>

#define NB 8
#define CCH 8
#define FF 257
#define TT 1000
#define AD 512
#define EPSI 1.1920928955078125e-07f
#define EPS5 1e-05f
#define NCHUNK 4
#define CHUNK 256

// pair indexing for Hermitian upper triangle (i<=j)
__host__ __device__ constexpr int PIDX(int i, int j) { return i * 8 - i * (i - 1) / 2 + (j - i); }        // 0..35
__host__ __device__ constexpr int QIDX(int i, int j) { return i * 7 - i * (i - 1) / 2 + (j - i - 1); }    // 0..27 (j>i)

// record layout per (n,f) (and per-chunk partials), stride 132 floats:
// [0..35]  sum mask*Re(s_i conj s_j)  (i<=j)   [RAW mask, not normalized]
// [36..63] sum mask*Im(s_i conj s_j) (i<j)
// [64..99] sum Re(s_i conj s_j)
// [100..127] sum Im(s_i conj s_j)
// [128] sum mask (raw)   [129] max |mask|
#define REC_STRIDE 132

__device__ inline float wredsum(float v) {
#pragma unroll
    for (int o = 32; o; o >>= 1) v += __shfl_down(v, o, 64);
    return v;
}
__device__ inline float wredmax(float v) {
#pragma unroll
    for (int o = 32; o; o >>= 1) v = fmaxf(v, __shfl_down(v, o, 64));
    return v;
}

// value-parallel butterfly: reduce a[0..63] across 64 lanes.
// On exit, lane L holds sum over all lanes of original a[L].
__device__ inline void bfly64(float a[64], int lane) {
#pragma unroll
    for (int m = 32; m >= 1; m >>= 1) {
        bool low = (lane & m) == 0;
#pragma unroll
        for (int p = 0; p < m; p++) {
            float send = low ? a[p + m] : a[p];
            float recv = __shfl_xor(send, m, 64);
            a[p] = (low ? a[p] : a[p + m]) + recv;
        }
    }
}

// one wave per (f, n, t-chunk); no LDS, no barriers; raw masked+unmasked sums
__global__ __launch_bounds__(64, 2) void cov_kernel(const float* __restrict__ mask,
                                                    const float* __restrict__ xr,
                                                    const float* __restrict__ xi,
                                                    float* __restrict__ part) {
    const int f = blockIdx.x;            // 0..256
    const int nc = blockIdx.y;           // 0..31
    const int n = nc >> 2, ch = nc & 3;
    const int lane = threadIdx.x;

    float accM[64] = {};
    float accU[64] = {};
    float smask = 0.f, mmask = 0.f;

    const size_t cstride = (size_t)FF * TT;
    const float* xrb = xr + ((size_t)(n * CCH) * FF + f) * TT;
    const float* xib = xi + ((size_t)(n * CCH) * FF + f) * TT;
    const float* mb = mask + (size_t)n * TT * FF + f;

#pragma unroll
    for (int it = 0; it < 4; ++it) {
        const int t = ch * CHUNK + it * 64 + lane;
        if (t < TT) {
            float mv = mb[(size_t)t * FF];
            smask += mv;
            mmask = fmaxf(mmask, fabsf(mv));
            float ar[8], ai[8];
#pragma unroll
            for (int c = 0; c < 8; c++) {
                ar[c] = xrb[c * cstride + t];
                ai[c] = xib[c * cstride + t];
            }
#pragma unroll
            for (int i = 0; i < 8; i++) {
                {
                    // diag: unmasked 2 fma, masked mul+fma+fma
                    accU[PIDX(i, i)] += ar[i] * ar[i];
                    accU[PIDX(i, i)] += ai[i] * ai[i];
                    float pr = ar[i] * ar[i] + ai[i] * ai[i];
                    accM[PIDX(i, i)] += mv * pr;
                }
#pragma unroll
                for (int j = i + 1; j < 8; j++) {
                    float pr = ar[i] * ar[j] + ai[i] * ai[j];
                    float pi = ai[i] * ar[j] - ar[i] * ai[j];
                    accU[PIDX(i, j)] += pr;
                    accU[36 + QIDX(i, j)] += pi;
                    accM[PIDX(i, j)] += mv * pr;
                    accM[36 + QIDX(i, j)] += mv * pi;
                }
            }
        }
    }

    bfly64(accM, lane);
    bfly64(accU, lane);
    float st = wredsum(smask);
    float mt = wredmax(mmask);

    float* rp = part + (size_t)((n * FF + f) * NCHUNK + ch) * REC_STRIDE;
    rp[lane] = accM[0];
    rp[64 + lane] = accU[0];
    if (lane == 0) { rp[128] = st; rp[129] = mt; }
}

__global__ void combine_kernel(const float* __restrict__ part, float* __restrict__ cov) {
    const int r = blockIdx.x;  // 0..2055
    const int tid = threadIdx.x;
    const float* p = part + (size_t)r * NCHUNK * REC_STRIDE;
    float* o = cov + (size_t)r * REC_STRIDE;
    for (int s = tid; s < 130; s += 64) {
        float a = p[s], b = p[REC_STRIDE + s], c = p[2 * REC_STRIDE + s], d = p[3 * REC_STRIDE + s];
        o[s] = (s == 129) ? fmaxf(fmaxf(a, b), fmaxf(c, d)) : (a + b + c + d);
    }
}

// grid (dc=8, n=8); wave q handles channels 2q,2q+1; lane = d within chunk
__global__ __launch_bounds__(256) void attn_kernel(const float* __restrict__ cov,
                                                   const float* __restrict__ proj_w,
                                                   const float* __restrict__ proj_b,
                                                   const float* __restrict__ gvec_w,
                                                   float* __restrict__ gpart) {
    const int dc = blockIdx.x;
    const int n = blockIdx.y;
    const int tid = threadIdx.x;
    __shared__ float feat[8][FF];

    for (int f = tid; f < FF; f += 256) {
        const float* rec = cov + (size_t)(n * FF + f) * REC_STRIDE;
        float inv_mx = 1.0f / (rec[129] + EPSI);
        float sum_ms = rec[128] * inv_mx;
        float scale = inv_mx / (7.0f * fmaxf(sum_ms, EPSI));
#pragma unroll
        for (int i = 0; i < 8; i++) {
            float rr = 0.f, ri = 0.f;
#pragma unroll
            for (int j = 0; j < 8; j++) {
                if (j == i) continue;
                if (j > i) { rr += rec[PIDX(i, j)]; ri += rec[36 + QIDX(i, j)]; }
                else       { rr += rec[PIDX(j, i)]; ri -= rec[36 + QIDX(j, i)]; }
            }
            feat[i][f] = sqrtf(rr * rr + ri * ri) * scale;
        }
    }
    __syncthreads();

    const int wv = tid >> 6, lane = tid & 63;
    const int d = dc * 64 + lane;
    const int c0 = 2 * wv, c1 = c0 + 1;
    const float* pwd = proj_w + (size_t)d * FF;
    float a0 = proj_b[d], a1 = a0;
    for (int f = 0; f < FF; f++) {
        float w = pwd[f];
        a0 += w * feat[c0][f];
        a1 += w * feat[c1][f];
    }
    float gwd = gvec_w[d];
    float g0 = gwd * tanhf(a0);
    float g1 = gwd * tanhf(a1);
    g0 = wredsum(g0);
    g1 = wredsum(g1);
    if (!lane) {
        gpart[(n * 8 + dc) * 8 + c0] = g0;
        gpart[(n * 8 + dc) * 8 + c1] = g1;
    }
}

__global__ void attn2_kernel(const float* __restrict__ gpart, const float* __restrict__ gvec_b,
                             float* __restrict__ u) {
    const int n = blockIdx.x;
    const int lane = threadIdx.x;  // 64: dc*8 + c
    float v = gpart[n * 64 + lane];
    v += __shfl_xor(v, 8, 64);
    v += __shfl_xor(v, 16, 64);
    v += __shfl_xor(v, 32, 64);
    float g = v + gvec_b[0];
    float m = g;
    m = fmaxf(m, __shfl_xor(m, 1, 64));
    m = fmaxf(m, __shfl_xor(m, 2, 64));
    m = fmaxf(m, __shfl_xor(m, 4, 64));
    float e = expf(g - m);
    float s = e;
    s += __shfl_xor(s, 1, 64);
    s += __shfl_xor(s, 2, 64);
    s += __shfl_xor(s, 4, 64);
    if (lane < 8) u[n * 8 + lane] = e / s;
}

__global__ __launch_bounds__(64, 1) void solve_kernel(const float* __restrict__ cov,
                                                      const float* __restrict__ u,
                                                      float* __restrict__ wout) {
    const int idx = blockIdx.x * 64 + threadIdx.x;
    if (idx >= NB * FF) return;
    const int n = idx / FF;
    const float* rec = cov + (size_t)idx * REC_STRIDE;

    float raw = rec[128], mx = rec[129];
    float inv_mx = 1.0f / (mx + EPSI);
    float sum_ms = raw * inv_mx;
    float inv_s = 1.0f / fmaxf(sum_ms, EPSI);
    float inv_n = 1.0f / fmaxf((float)TT - sum_ms, EPSI);
    float ks = inv_mx * inv_s;   // Rs entry scale on raw masked sums

    float Ar[8][8], Ai[8][8], Br[8][8], Bi[8][8];  // A = Rn, B = Rs -> X
#pragma unroll
    for (int i = 0; i < 8; i++) {
#pragma unroll
        for (int j = i; j < 8; j++) {
            float mr = rec[PIDX(i, j)];
            float tr = rec[64 + PIDX(i, j)];
            float s_r = mr * ks;
            float n_r = (tr - mr * inv_mx) * inv_n;
            if (j == i) {
                Br[i][i] = s_r; Bi[i][i] = 0.f;
                Ar[i][i] = n_r + EPS5; Ai[i][i] = 0.f;
            } else {
                float mi = rec[36 + QIDX(i, j)];
                float ti = rec[100 + QIDX(i, j)];
                float s_i = mi * ks;
                float n_i = (ti - mi * inv_mx) * inv_n;
                Br[i][j] = s_r; Bi[i][j] = s_i;
                Br[j][i] = s_r; Bi[j][i] = -s_i;
                Ar[i][j] = n_r; Ai[i][j] = n_i;
                Ar[j][i] = n_r; Ai[j][i] = -n_i;
            }
        }
    }

    // forward elimination (no pivot: A is HPD + eps*I)
#pragma unroll
    for (int k = 0; k < 8; k++) {
        float dr = Ar[k][k], di = Ai[k][k];
        float iv = 1.0f / (dr * dr + di * di);
        float pir = dr * iv, pii = -di * iv;
#pragma unroll
        for (int r = k + 1; r < 8; r++) {
            float ar = Ar[r][k], ai = Ai[r][k];
            float fr = ar * pir - ai * pii;
            float fi = ar * pii + ai * pir;
#pragma unroll
            for (int j = k + 1; j < 8; j++) {
                Ar[r][j] -= fr * Ar[k][j] - fi * Ai[k][j];
                Ai[r][j] -= fr * Ai[k][j] + fi * Ar[k][j];
            }
#pragma unroll
            for (int j = 0; j < 8; j++) {
                Br[r][j] -= fr * Br[k][j] - fi * Bi[k][j];
                Bi[r][j] -= fr * Bi[k][j] + fi * Br[k][j];
            }
        }
    }
    // back substitution
#pragma unroll
    for (int k = 7; k >= 0; k--) {
        float dr = Ar[k][k], di = Ai[k][k];
        float iv = 1.0f / (dr * dr + di * di);
        float pir = dr * iv, pii = -di * iv;
#pragma unroll
        for (int j = 0; j < 8; j++) {
            float s_r = Br[k][j], s_i = Bi[k][j];
#pragma unroll
            for (int m = k + 1; m < 8; m++) {
                s_r -= Ar[k][m] * Br[m][j] - Ai[k][m] * Bi[m][j];
                s_i -= Ar[k][m] * Bi[m][j] + Ai[k][m] * Br[m][j];
            }
            Br[k][j] = s_r * pir - s_i * pii;
            Bi[k][j] = s_r * pii + s_i * pir;
        }
    }

    float trr = EPS5, tri = 0.f;
#pragma unroll
    for (int i = 0; i < 8; i++) { trr += Br[i][i]; tri += Bi[i][i]; }
    float tinv = 1.0f / (trr * trr + tri * tri);

    float* wo = wout + (size_t)idx * 16;
#pragma unroll
    for (int i = 0; i < 8; i++) {
        float nr = 0.f, ni = 0.f;
#pragma unroll
        for (int c = 0; c < 8; c++) {
            float uc = u[n * 8 + c];
            nr += Br[i][c] * uc;
            ni += Bi[i][c] * uc;
        }
        float wr = (nr * trr + ni * tri) * tinv;
        float wi = (ni * trr - nr * tri) * tinv;
        wo[i * 2] = wr;        // store conj(w): real
        wo[i * 2 + 1] = -wi;   // store conj(w): imag
    }
}

__global__ __launch_bounds__(256) void beam_kernel(const float* __restrict__ xr,
                                                   const float* __restrict__ xi,
                                                   const float* __restrict__ wc,
                                                   float* __restrict__ out) {
    const int n = blockIdx.z;
    const int f0 = blockIdx.y * 32;
    const int t0 = blockIdx.x * 64;
    const int tid = threadIdx.x;

    __shared__ float wlds[32][16];
    __shared__ float bldr[32][65];
    __shared__ float bldi[32][65];

    for (int s = tid; s < 32 * 16; s += 256) {
        int fl = s >> 4, rest = s & 15;
        int f = f0 + fl;
        wlds[fl][rest] = (f < FF) ? wc[(size_t)(n * FF + f) * 16 + rest] : 0.f;
    }
    __syncthreads();

    const int lane_t = tid & 63, row = tid >> 6;
    const int t = t0 + lane_t;
    const bool tok = t < TT;
    const size_t cstride = (size_t)FF * TT;

#pragma unroll
    for (int k = 0; k < 8; k++) {
        int fl = row + k * 4;
        int f = f0 + fl;
        float br = 0.f, bi = 0.f;
        if (f < FF && tok) {
            size_t base = ((size_t)(n * CCH) * FF + f) * TT + t;
#pragma unroll
            for (int c = 0; c < 8; c++) {
                float vr = xr[base + c * cstride];
                float vi = xi[base + c * cstride];
                float wr = wlds[fl][c * 2], wi_ = wlds[fl][c * 2 + 1];
                br += wr * vr - wi_ * vi;
                bi += wr * vi + wi_ * vr;
            }
        }
        bldr[fl][lane_t] = br;
        bldi[fl][lane_t] = bi;
    }
    __syncthreads();

    const int fc = tid & 31, trb = tid >> 5;
    const int f = f0 + fc;
    float2* outv = (float2*)out;
#pragma unroll
    for (int k = 0; k < 8; k++) {
        int tr = trb + k * 8;
        int t2 = t0 + tr;
        if (f < FF && t2 < TT) {
            float2 v = make_float2(bldr[fc][tr], bldi[fc][tr]);
            outv[(size_t)(n * TT + t2) * FF + f] = v;
        }
    }
}

extern "C" void kernel_launch(void* const* d_in, const int* in_sizes, int n_in,
                              void* d_out, int out_size, void* d_ws, size_t ws_size,
                              hipStream_t stream) {
    const float* mask = (const float*)d_in[0];
    const float* xr = (const float*)d_in[1];
    const float* xi = (const float*)d_in[2];
    const float* pw = (const float*)d_in[3];
    const float* pb = (const float*)d_in[4];
    const float* gw = (const float*)d_in[5];
    const float* gb = (const float*)d_in[6];
    float* out = (float*)d_out;
    float* ws = (float*)d_ws;

    float* part = ws;                                            // 2056*4*132
    float* cov = part + (size_t)NB * FF * NCHUNK * REC_STRIDE;   // 2056*132
    float* gpart = cov + (size_t)NB * FF * REC_STRIDE;           // 8*8*8
    float* u = gpart + 512;                                      // 64
    float* wv = u + 64;                                          // 2056*16

    hipLaunchKernelGGL(cov_kernel, dim3(FF, NB * NCHUNK), dim3(64), 0, stream, mask, xr, xi, part);
    hipLaunchKernelGGL(combine_kernel, dim3(NB * FF), dim3(64), 0, stream, part, cov);
    hipLaunchKernelGGL(attn_kernel, dim3(8, NB), dim3(256), 0, stream, cov, pw, pb, gw, gpart);
    hipLaunchKernelGGL(attn2_kernel, dim3(NB), dim3(64), 0, stream, gpart, gb, u);
    hipLaunchKernelGGL(solve_kernel, dim3((NB * FF + 63) / 64), dim3(64), 0, stream, cov, u, wv);
    hipLaunchKernelGGL(beam_kernel, dim3((TT + 63) / 64, (FF + 31) / 32, NB), dim3(256), 0, stream, xr, xi, wv, out);
}

// Round 4
// 347.081 us; speedup vs baseline: 1.4821x; 1.4821x over previous
//
#include <hip/hip_runtime.h>
#include <hip/hip_bf16.h>
#include <cmath>

#define NB 8
#define CCH 8
#define FF 257
#define TT 1000
#define AD 512
#define EPSI 1.1920928955078125e-07f
#define EPS5 1e-05f

// pair indexing for Hermitian upper triangle (i<=j)
__host__ __device__ constexpr int PIDX(int i, int j) { return i * 8 - i * (i - 1) / 2 + (j - i); }        // 0..35
__host__ __device__ constexpr int QIDX(int i, int j) { return i * 7 - i * (i - 1) / 2 + (j - i - 1); }    // 0..27 (j>i)

// final record layout per (n,f), stride 132 floats:
// [0..35]  sum mask*Re(s_i conj s_j)  (i<=j)   [RAW mask, not normalized]
// [36..63] sum mask*Im(s_i conj s_j) (i<j)
// [64..99] sum Re(s_i conj s_j)
// [100..127] sum Im(s_i conj s_j)
// [128] sum mask (raw)   [129] max |mask|
#define REC_STRIDE 132
// partial record stride (per (n,f,kind,chunk)): [0..63] acc, [64] sum mask, [65] max|mask|
#define PSTRIDE 68
#define TCHUNK 500

__device__ inline float wredsum(float v) {
#pragma unroll
    for (int o = 32; o; o >>= 1) v += __shfl_down(v, o, 64);
    return v;
}
__device__ inline float wredmax(float v) {
#pragma unroll
    for (int o = 32; o; o >>= 1) v = fmaxf(v, __shfl_down(v, o, 64));
    return v;
}

// value-parallel butterfly: reduce a[0..63] across 64 lanes.
// On exit, lane L's a[0] holds the total of original a[L] (proven in round 3).
__device__ inline void bfly64(float a[64], int lane) {
#pragma unroll
    for (int m = 32; m >= 1; m >>= 1) {
        bool low = (lane & m) == 0;
#pragma unroll
        for (int p = 0; p < m; p++) {
            float send = low ? a[p + m] : a[p];
            float recv = __shfl_xor(send, m, 64);
            a[p] = (low ? a[p] : a[p + m]) + recv;
        }
    }
}

// one wave per (f, n, kind, t-chunk); no LDS, no barriers.
// kind 0: mask-weighted sums (+ mask sum/max). kind 1: unmasked sums.
// 64 accumulators/thread — stays register-allocated (128 spills; learned r3).
__global__ __launch_bounds__(64, 2) void cov_part_kernel(const float* __restrict__ mask,
                                                         const float* __restrict__ xr,
                                                         const float* __restrict__ xi,
                                                         float* __restrict__ part) {
    const int f = blockIdx.x;            // 0..256
    const int n = blockIdx.y;            // 0..7
    const int z = blockIdx.z;            // kind*2 + chunk
    const int kind = z >> 1, ch = z & 1;
    const int lane = threadIdx.x;
    const int t0 = ch * TCHUNK;

    float acc[64] = {};
    float smask = 0.f, mmask = 0.f;

    const size_t cstride = (size_t)FF * TT;
    const float* xrb = xr + ((size_t)(n * CCH) * FF + f) * TT;
    const float* xib = xi + ((size_t)(n * CCH) * FF + f) * TT;
    const float* mb = mask + (size_t)n * TT * FF + f;

#pragma unroll
    for (int it = 0; it < 8; ++it) {
        const int tt = it * 64 + lane;
        if (it == 7 && tt >= TCHUNK) continue;   // 500 = 7*64 + 52
        const int t = t0 + tt;
        float w;
        if (kind == 0) {
            float mv = mb[(size_t)t * FF];
            smask += mv;
            mmask = fmaxf(mmask, fabsf(mv));
            w = mv;
        } else {
            w = 1.0f;
        }
        float ar[8], ai[8];
#pragma unroll
        for (int c = 0; c < 8; c++) {
            ar[c] = xrb[c * cstride + t];
            ai[c] = xib[c * cstride + t];
        }
#pragma unroll
        for (int i = 0; i < 8; i++) {
            {
                float pr = ar[i] * ar[i] + ai[i] * ai[i];
                acc[PIDX(i, i)] += w * pr;
            }
#pragma unroll
            for (int j = i + 1; j < 8; j++) {
                float pr = ar[i] * ar[j] + ai[i] * ai[j];
                float pi = ai[i] * ar[j] - ar[i] * ai[j];
                acc[PIDX(i, j)] += w * pr;
                acc[36 + QIDX(i, j)] += w * pi;
            }
        }
    }

    bfly64(acc, lane);

    float* rp = part + (size_t)(((n * FF + f) * 4) + z) * PSTRIDE;
    rp[lane] = acc[0];
    if (kind == 0) {
        float st = wredsum(smask);
        float mt = wredmax(mmask);
        if (lane == 0) { rp[64] = st; rp[65] = mt; }
    }
}

__global__ void combine_kernel(const float* __restrict__ part, float* __restrict__ cov) {
    const int r = blockIdx.x;  // 0..2055
    const int lane = threadIdx.x;
    const float* p = part + (size_t)r * 4 * PSTRIDE;
    float* o = cov + (size_t)r * REC_STRIDE;
    o[lane] = p[lane] + p[PSTRIDE + lane];                          // masked sums
    o[64 + lane] = p[2 * PSTRIDE + lane] + p[3 * PSTRIDE + lane];   // unmasked sums
    if (lane == 0) {
        o[128] = p[64] + p[PSTRIDE + 64];
        o[129] = fmaxf(p[65], p[PSTRIDE + 65]);
    }
}

// grid (dc=8, n=8); wave q handles channels 2q,2q+1; lane = d within chunk
__global__ __launch_bounds__(256) void attn_kernel(const float* __restrict__ cov,
                                                   const float* __restrict__ proj_w,
                                                   const float* __restrict__ proj_b,
                                                   const float* __restrict__ gvec_w,
                                                   float* __restrict__ gpart) {
    const int dc = blockIdx.x;
    const int n = blockIdx.y;
    const int tid = threadIdx.x;
    __shared__ float feat[8][FF];

    for (int f = tid; f < FF; f += 256) {
        const float* rec = cov + (size_t)(n * FF + f) * REC_STRIDE;
        float inv_mx = 1.0f / (rec[129] + EPSI);
        float sum_ms = rec[128] * inv_mx;
        float scale = inv_mx / (7.0f * fmaxf(sum_ms, EPSI));
#pragma unroll
        for (int i = 0; i < 8; i++) {
            float rr = 0.f, ri = 0.f;
#pragma unroll
            for (int j = 0; j < 8; j++) {
                if (j == i) continue;
                if (j > i) { rr += rec[PIDX(i, j)]; ri += rec[36 + QIDX(i, j)]; }
                else       { rr += rec[PIDX(j, i)]; ri -= rec[36 + QIDX(j, i)]; }
            }
            feat[i][f] = sqrtf(rr * rr + ri * ri) * scale;
        }
    }
    __syncthreads();

    const int wv = tid >> 6, lane = tid & 63;
    const int d = dc * 64 + lane;
    const int c0 = 2 * wv, c1 = c0 + 1;
    const float* pwd = proj_w + (size_t)d * FF;
    float a0 = proj_b[d], a1 = a0;
    for (int f = 0; f < FF; f++) {
        float w = pwd[f];
        a0 += w * feat[c0][f];
        a1 += w * feat[c1][f];
    }
    float gwd = gvec_w[d];
    float g0 = gwd * tanhf(a0);
    float g1 = gwd * tanhf(a1);
    g0 = wredsum(g0);
    g1 = wredsum(g1);
    if (!lane) {
        gpart[(n * 8 + dc) * 8 + c0] = g0;
        gpart[(n * 8 + dc) * 8 + c1] = g1;
    }
}

__global__ void attn2_kernel(const float* __restrict__ gpart, const float* __restrict__ gvec_b,
                             float* __restrict__ u) {
    const int n = blockIdx.x;
    const int lane = threadIdx.x;  // 64: dc*8 + c
    float v = gpart[n * 64 + lane];
    v += __shfl_xor(v, 8, 64);
    v += __shfl_xor(v, 16, 64);
    v += __shfl_xor(v, 32, 64);
    float g = v + gvec_b[0];
    float m = g;
    m = fmaxf(m, __shfl_xor(m, 1, 64));
    m = fmaxf(m, __shfl_xor(m, 2, 64));
    m = fmaxf(m, __shfl_xor(m, 4, 64));
    float e = expf(g - m);
    float s = e;
    s += __shfl_xor(s, 1, 64);
    s += __shfl_xor(s, 2, 64);
    s += __shfl_xor(s, 4, 64);
    if (lane < 8) u[n * 8 + lane] = e / s;
}

__global__ __launch_bounds__(64, 1) void solve_kernel(const float* __restrict__ cov,
                                                      const float* __restrict__ u,
                                                      float* __restrict__ wout) {
    const int idx = blockIdx.x * 64 + threadIdx.x;
    if (idx >= NB * FF) return;
    const int n = idx / FF;
    const float* rec = cov + (size_t)idx * REC_STRIDE;

    float raw = rec[128], mx = rec[129];
    float inv_mx = 1.0f / (mx + EPSI);
    float sum_ms = raw * inv_mx;
    float inv_s = 1.0f / fmaxf(sum_ms, EPSI);
    float inv_n = 1.0f / fmaxf((float)TT - sum_ms, EPSI);
    float ks = inv_mx * inv_s;   // Rs entry scale on raw masked sums

    float Ar[8][8], Ai[8][8], Br[8][8], Bi[8][8];  // A = Rn, B = Rs -> X
#pragma unroll
    for (int i = 0; i < 8; i++) {
#pragma unroll
        for (int j = i; j < 8; j++) {
            float mr = rec[PIDX(i, j)];
            float tr = rec[64 + PIDX(i, j)];
            float s_r = mr * ks;
            float n_r = (tr - mr * inv_mx) * inv_n;
            if (j == i) {
                Br[i][i] = s_r; Bi[i][i] = 0.f;
                Ar[i][i] = n_r + EPS5; Ai[i][i] = 0.f;
            } else {
                float mi = rec[36 + QIDX(i, j)];
                float ti = rec[100 + QIDX(i, j)];
                float s_i = mi * ks;
                float n_i = (ti - mi * inv_mx) * inv_n;
                Br[i][j] = s_r; Bi[i][j] = s_i;
                Br[j][i] = s_r; Bi[j][i] = -s_i;
                Ar[i][j] = n_r; Ai[i][j] = n_i;
                Ar[j][i] = n_r; Ai[j][i] = -n_i;
            }
        }
    }

    // forward elimination (no pivot: A is HPD + eps*I)
#pragma unroll
    for (int k = 0; k < 8; k++) {
        float dr = Ar[k][k], di = Ai[k][k];
        float iv = 1.0f / (dr * dr + di * di);
        float pir = dr * iv, pii = -di * iv;
#pragma unroll
        for (int r = k + 1; r < 8; r++) {
            float ar = Ar[r][k], ai = Ai[r][k];
            float fr = ar * pir - ai * pii;
            float fi = ar * pii + ai * pir;
#pragma unroll
            for (int j = k + 1; j < 8; j++) {
                Ar[r][j] -= fr * Ar[k][j] - fi * Ai[k][j];
                Ai[r][j] -= fr * Ai[k][j] + fi * Ar[k][j];
            }
#pragma unroll
            for (int j = 0; j < 8; j++) {
                Br[r][j] -= fr * Br[k][j] - fi * Bi[k][j];
                Bi[r][j] -= fr * Bi[k][j] + fi * Br[k][j];
            }
        }
    }
    // back substitution
#pragma unroll
    for (int k = 7; k >= 0; k--) {
        float dr = Ar[k][k], di = Ai[k][k];
        float iv = 1.0f / (dr * dr + di * di);
        float pir = dr * iv, pii = -di * iv;
#pragma unroll
        for (int j = 0; j < 8; j++) {
            float s_r = Br[k][j], s_i = Bi[k][j];
#pragma unroll
            for (int m = k + 1; m < 8; m++) {
                s_r -= Ar[k][m] * Br[m][j] - Ai[k][m] * Bi[m][j];
                s_i -= Ar[k][m] * Bi[m][j] + Ai[k][m] * Br[m][j];
            }
            Br[k][j] = s_r * pir - s_i * pii;
            Bi[k][j] = s_r * pii + s_i * pir;
        }
    }

    float trr = EPS5, tri = 0.f;
#pragma unroll
    for (int i = 0; i < 8; i++) { trr += Br[i][i]; tri += Bi[i][i]; }
    float tinv = 1.0f / (trr * trr + tri * tri);

    float* wo = wout + (size_t)idx * 16;
#pragma unroll
    for (int i = 0; i < 8; i++) {
        float nr = 0.f, ni = 0.f;
#pragma unroll
        for (int c = 0; c < 8; c++) {
            float uc = u[n * 8 + c];
            nr += Br[i][c] * uc;
            ni += Bi[i][c] * uc;
        }
        float wr = (nr * trr + ni * tri) * tinv;
        float wi = (ni * trr - nr * tri) * tinv;
        wo[i * 2] = wr;        // store conj(w): real
        wo[i * 2 + 1] = -wi;   // store conj(w): imag
    }
}

__global__ __launch_bounds__(256) void beam_kernel(const float* __restrict__ xr,
                                                   const float* __restrict__ xi,
                                                   const float* __restrict__ wc,
                                                   float* __restrict__ out) {
    const int n = blockIdx.z;
    const int f0 = blockIdx.y * 32;
    const int t0 = blockIdx.x * 64;
    const int tid = threadIdx.x;

    __shared__ float wlds[32][16];
    __shared__ float bldr[32][65];
    __shared__ float bldi[32][65];

    for (int s = tid; s < 32 * 16; s += 256) {
        int fl = s >> 4, rest = s & 15;
        int f = f0 + fl;
        wlds[fl][rest] = (f < FF) ? wc[(size_t)(n * FF + f) * 16 + rest] : 0.f;
    }
    __syncthreads();

    const int lane_t = tid & 63, row = tid >> 6;
    const int t = t0 + lane_t;
    const bool tok = t < TT;
    const size_t cstride = (size_t)FF * TT;

#pragma unroll
    for (int k = 0; k < 8; k++) {
        int fl = row + k * 4;
        int f = f0 + fl;
        float br = 0.f, bi = 0.f;
        if (f < FF && tok) {
            size_t base = ((size_t)(n * CCH) * FF + f) * TT + t;
#pragma unroll
            for (int c = 0; c < 8; c++) {
                float vr = xr[base + c * cstride];
                float vi = xi[base + c * cstride];
                float wr = wlds[fl][c * 2], wi_ = wlds[fl][c * 2 + 1];
                br += wr * vr - wi_ * vi;
                bi += wr * vi + wi_ * vr;
            }
        }
        bldr[fl][lane_t] = br;
        bldi[fl][lane_t] = bi;
    }
    __syncthreads();

    const int fc = tid & 31, trb = tid >> 5;
    const int f = f0 + fc;
    float2* outv = (float2*)out;
#pragma unroll
    for (int k = 0; k < 8; k++) {
        int tr = trb + k * 8;
        int t2 = t0 + tr;
        if (f < FF && t2 < TT) {
            float2 v = make_float2(bldr[fc][tr], bldi[fc][tr]);
            outv[(size_t)(n * TT + t2) * FF + f] = v;
        }
    }
}

extern "C" void kernel_launch(void* const* d_in, const int* in_sizes, int n_in,
                              void* d_out, int out_size, void* d_ws, size_t ws_size,
                              hipStream_t stream) {
    const float* mask = (const float*)d_in[0];
    const float* xr = (const float*)d_in[1];
    const float* xi = (const float*)d_in[2];
    const float* pw = (const float*)d_in[3];
    const float* pb = (const float*)d_in[4];
    const float* gw = (const float*)d_in[5];
    const float* gb = (const float*)d_in[6];
    float* out = (float*)d_out;
    float* ws = (float*)d_ws;

    float* part = ws;                                            // 2056*4*68
    float* cov = part + (size_t)NB * FF * 4 * PSTRIDE;           // 2056*132
    float* gpart = cov + (size_t)NB * FF * REC_STRIDE;           // 512
    float* u = gpart + 512;                                      // 64
    float* wv = u + 64;                                          // 2056*16

    hipLaunchKernelGGL(cov_part_kernel, dim3(FF, NB, 4), dim3(64), 0, stream, mask, xr, xi, part);
    hipLaunchKernelGGL(combine_kernel, dim3(NB * FF), dim3(64), 0, stream, part, cov);
    hipLaunchKernelGGL(attn_kernel, dim3(8, NB), dim3(256), 0, stream, cov, pw, pb, gw, gpart);
    hipLaunchKernelGGL(attn2_kernel, dim3(NB), dim3(64), 0, stream, gpart, gb, u);
    hipLaunchKernelGGL(solve_kernel, dim3((NB * FF + 63) / 64), dim3(64), 0, stream, cov, u, wv);
    hipLaunchKernelGGL(beam_kernel, dim3((TT + 63) / 64, (FF + 31) / 32, NB), dim3(256), 0, stream, xr, xi, wv, out);
}

// Round 5
// 228.591 us; speedup vs baseline: 2.2504x; 1.5184x over previous
//
#include <hip/hip_runtime.h>
#include <hip/hip_bf16.h>
#include <cmath>

#define NB 8
#define CCH 8
#define FF 257
#define TT 1000
#define AD 512
#define EPSI 1.1920928955078125e-07f
#define EPS5 1e-05f
#define NCH 2
#define TCH 500

// pair indexing for Hermitian upper triangle (i<=j)
__host__ __device__ constexpr int PIDX(int i, int j) { return i * 8 - i * (i - 1) / 2 + (j - i); }        // 0..35
__host__ __device__ constexpr int QIDX(int i, int j) { return i * 7 - i * (i - 1) / 2 + (j - i - 1); }    // 0..27 (j>i)

// e -> (i,j) tables for the two triangles (compile-time folded in unrolled loops)
__device__ constexpr int RI_[36] = {0,0,0,0,0,0,0,0, 1,1,1,1,1,1,1, 2,2,2,2,2,2, 3,3,3,3,3, 4,4,4,4, 5,5,5, 6,6, 7};
__device__ constexpr int RJ_[36] = {0,1,2,3,4,5,6,7, 1,2,3,4,5,6,7, 2,3,4,5,6,7, 3,4,5,6,7, 4,5,6,7, 5,6,7, 6,7, 7};
__device__ constexpr int QI_[28] = {0,0,0,0,0,0,0, 1,1,1,1,1,1, 2,2,2,2,2, 3,3,3,3, 4,4,4, 5,5, 6};
__device__ constexpr int QJ_[28] = {1,2,3,4,5,6,7, 2,3,4,5,6,7, 3,4,5,6,7, 4,5,6,7, 5,6,7, 6,7, 7};

// final record layout per (n,f), stride 132 floats:
// [0..35]  sum mask*Re(s_i conj s_j)  (i<=j)   [RAW mask, not normalized]
// [36..63] sum mask*Im(s_i conj s_j) (i<j)
// [64..99] sum Re(s_i conj s_j)
// [100..127] sum Im(s_i conj s_j)
// [128] sum mask (raw)   [129] max |mask|
#define REC_STRIDE 132

__device__ inline float wredsum(float v) {
#pragma unroll
    for (int o = 32; o; o >>= 1) v += __shfl_down(v, o, 64);
    return v;
}
__device__ inline float wredmax(float v) {
#pragma unroll
    for (int o = 32; o; o >>= 1) v = fmaxf(v, __shfl_down(v, o, 64));
    return v;
}

// one wave per (kind, f, n*chunk). kind on FASTEST grid dim -> the 4 kinds'
// reads of the same x slice are temporally adjacent -> L2/L3 absorb 3 of 4.
// kind 0: masked-real(36)+mask stats  1: masked-imag(28)
// kind 2: unmasked-real(36)           3: unmasked-imag(28)
// <=36 accumulators/thread -> registers (64 spilled in r3/r4).
// Atomic finish: kinds hit disjoint record offsets; each offset has exactly
// 2 commutative contributors (chunks) -> bitwise deterministic.
__global__ __launch_bounds__(64, 4) void cov_part_kernel(const float* __restrict__ mask,
                                                         const float* __restrict__ xr,
                                                         const float* __restrict__ xi,
                                                         float* __restrict__ cov) {
    const int kind = blockIdx.x;         // 0..3
    const int f = blockIdx.y;            // 0..256
    const int z = blockIdx.z;            // n*NCH + ch
    const int n = z >> 1, ch = z & 1;
    const int lane = threadIdx.x;
    const int t0 = ch * TCH;
    const bool isReal = (kind & 1) == 0;
    const bool isMasked = kind < 2;

    float acc[36] = {};
    float smask = 0.f, mmask = 0.f;

    const size_t cstride = (size_t)FF * TT;
    const float* xrb = xr + ((size_t)(n * CCH) * FF + f) * TT;
    const float* xib = xi + ((size_t)(n * CCH) * FF + f) * TT;
    const float* mb = mask + (size_t)n * TT * FF + f;

#pragma unroll
    for (int it = 0; it < 8; ++it) {
        const int tt = it * 64 + lane;
        if (tt < TCH) {                  // 500 = 7*64 + 52
            const int t = t0 + tt;
            float w = 1.0f;
            if (isMasked) {
                float mv = mb[(size_t)t * FF];
                w = mv;
                if (kind == 0) { smask += mv; mmask = fmaxf(mmask, fabsf(mv)); }
            }
            float ar[8], ai[8];
#pragma unroll
            for (int c = 0; c < 8; c++) {
                ar[c] = xrb[c * cstride + t];
                ai[c] = xib[c * cstride + t];
            }
            if (isReal) {
#pragma unroll
                for (int e = 0; e < 36; e++)
                    acc[e] += w * (ar[RI_[e]] * ar[RJ_[e]] + ai[RI_[e]] * ai[RJ_[e]]);
            } else {
#pragma unroll
                for (int e = 0; e < 28; e++)
                    acc[e] += w * (ai[QI_[e]] * ar[QJ_[e]] - ar[QI_[e]] * ai[QJ_[e]]);
            }
        }
    }

    float* rec = cov + (size_t)(n * FF + f) * REC_STRIDE;
    const int base = (kind == 0) ? 0 : (kind == 1) ? 36 : (kind == 2) ? 64 : 100;
    if (isReal) {
#pragma unroll
        for (int e = 0; e < 36; e++) {
            float v = wredsum(acc[e]);
            if (lane == 0) atomicAdd(&rec[base + e], v);
        }
    } else {
#pragma unroll
        for (int e = 0; e < 28; e++) {
            float v = wredsum(acc[e]);
            if (lane == 0) atomicAdd(&rec[base + e], v);
        }
    }
    if (kind == 0) {
        float st = wredsum(smask);
        float mt = wredmax(mmask);
        if (lane == 0) {
            atomicAdd(&rec[128], st);
            atomicMax((int*)&rec[129], __float_as_int(mt));  // valid: mask >= 0, init 0.0
        }
    }
}

// grid (dc=8, n=8); wave q handles channels 2q,2q+1; lane = d within chunk
__global__ __launch_bounds__(256) void attn_kernel(const float* __restrict__ cov,
                                                   const float* __restrict__ proj_w,
                                                   const float* __restrict__ proj_b,
                                                   const float* __restrict__ gvec_w,
                                                   float* __restrict__ gpart) {
    const int dc = blockIdx.x;
    const int n = blockIdx.y;
    const int tid = threadIdx.x;
    __shared__ float feat[8][FF];

    for (int f = tid; f < FF; f += 256) {
        const float* rec = cov + (size_t)(n * FF + f) * REC_STRIDE;
        float inv_mx = 1.0f / (rec[129] + EPSI);
        float sum_ms = rec[128] * inv_mx;
        float scale = inv_mx / (7.0f * fmaxf(sum_ms, EPSI));
#pragma unroll
        for (int i = 0; i < 8; i++) {
            float rr = 0.f, ri = 0.f;
#pragma unroll
            for (int j = 0; j < 8; j++) {
                if (j == i) continue;
                if (j > i) { rr += rec[PIDX(i, j)]; ri += rec[36 + QIDX(i, j)]; }
                else       { rr += rec[PIDX(j, i)]; ri -= rec[36 + QIDX(j, i)]; }
            }
            feat[i][f] = sqrtf(rr * rr + ri * ri) * scale;
        }
    }
    __syncthreads();

    const int wv = tid >> 6, lane = tid & 63;
    const int d = dc * 64 + lane;
    const int c0 = 2 * wv, c1 = c0 + 1;
    const float* pwd = proj_w + (size_t)d * FF;
    float a0 = proj_b[d], a1 = a0;
    for (int f = 0; f < FF; f++) {
        float w = pwd[f];
        a0 += w * feat[c0][f];
        a1 += w * feat[c1][f];
    }
    float gwd = gvec_w[d];
    float g0 = gwd * tanhf(a0);
    float g1 = gwd * tanhf(a1);
    g0 = wredsum(g0);
    g1 = wredsum(g1);
    if (!lane) {
        gpart[(n * 8 + dc) * 8 + c0] = g0;
        gpart[(n * 8 + dc) * 8 + c1] = g1;
    }
}

__global__ void attn2_kernel(const float* __restrict__ gpart, const float* __restrict__ gvec_b,
                             float* __restrict__ u) {
    const int n = blockIdx.x;
    const int lane = threadIdx.x;  // 64: dc*8 + c
    float v = gpart[n * 64 + lane];
    v += __shfl_xor(v, 8, 64);
    v += __shfl_xor(v, 16, 64);
    v += __shfl_xor(v, 32, 64);
    float g = v + gvec_b[0];
    float m = g;
    m = fmaxf(m, __shfl_xor(m, 1, 64));
    m = fmaxf(m, __shfl_xor(m, 2, 64));
    m = fmaxf(m, __shfl_xor(m, 4, 64));
    float e = expf(g - m);
    float s = e;
    s += __shfl_xor(s, 1, 64);
    s += __shfl_xor(s, 2, 64);
    s += __shfl_xor(s, 4, 64);
    if (lane < 8) u[n * 8 + lane] = e / s;
}

__global__ __launch_bounds__(64, 1) void solve_kernel(const float* __restrict__ cov,
                                                      const float* __restrict__ u,
                                                      float* __restrict__ wout) {
    const int idx = blockIdx.x * 64 + threadIdx.x;
    if (idx >= NB * FF) return;
    const int n = idx / FF;
    const float* rec = cov + (size_t)idx * REC_STRIDE;

    float raw = rec[128], mx = rec[129];
    float inv_mx = 1.0f / (mx + EPSI);
    float sum_ms = raw * inv_mx;
    float inv_s = 1.0f / fmaxf(sum_ms, EPSI);
    float inv_n = 1.0f / fmaxf((float)TT - sum_ms, EPSI);
    float ks = inv_mx * inv_s;   // Rs entry scale on raw masked sums

    float Ar[8][8], Ai[8][8], Br[8][8], Bi[8][8];  // A = Rn, B = Rs -> X
#pragma unroll
    for (int i = 0; i < 8; i++) {
#pragma unroll
        for (int j = i; j < 8; j++) {
            float mr = rec[PIDX(i, j)];
            float tr = rec[64 + PIDX(i, j)];
            float s_r = mr * ks;
            float n_r = (tr - mr * inv_mx) * inv_n;
            if (j == i) {
                Br[i][i] = s_r; Bi[i][i] = 0.f;
                Ar[i][i] = n_r + EPS5; Ai[i][i] = 0.f;
            } else {
                float mi = rec[36 + QIDX(i, j)];
                float ti = rec[100 + QIDX(i, j)];
                float s_i = mi * ks;
                float n_i = (ti - mi * inv_mx) * inv_n;
                Br[i][j] = s_r; Bi[i][j] = s_i;
                Br[j][i] = s_r; Bi[j][i] = -s_i;
                Ar[i][j] = n_r; Ai[i][j] = n_i;
                Ar[j][i] = n_r; Ai[j][i] = -n_i;
            }
        }
    }

    // forward elimination (no pivot: A is HPD + eps*I)
#pragma unroll
    for (int k = 0; k < 8; k++) {
        float dr = Ar[k][k], di = Ai[k][k];
        float iv = 1.0f / (dr * dr + di * di);
        float pir = dr * iv, pii = -di * iv;
#pragma unroll
        for (int r = k + 1; r < 8; r++) {
            float ar = Ar[r][k], ai = Ai[r][k];
            float fr = ar * pir - ai * pii;
            float fi = ar * pii + ai * pir;
#pragma unroll
            for (int j = k + 1; j < 8; j++) {
                Ar[r][j] -= fr * Ar[k][j] - fi * Ai[k][j];
                Ai[r][j] -= fr * Ai[k][j] + fi * Ar[k][j];
            }
#pragma unroll
            for (int j = 0; j < 8; j++) {
                Br[r][j] -= fr * Br[k][j] - fi * Bi[k][j];
                Bi[r][j] -= fr * Bi[k][j] + fi * Br[k][j];
            }
        }
    }
    // back substitution
#pragma unroll
    for (int k = 7; k >= 0; k--) {
        float dr = Ar[k][k], di = Ai[k][k];
        float iv = 1.0f / (dr * dr + di * di);
        float pir = dr * iv, pii = -di * iv;
#pragma unroll
        for (int j = 0; j < 8; j++) {
            float s_r = Br[k][j], s_i = Bi[k][j];
#pragma unroll
            for (int m = k + 1; m < 8; m++) {
                s_r -= Ar[k][m] * Br[m][j] - Ai[k][m] * Bi[m][j];
                s_i -= Ar[k][m] * Bi[m][j] + Ai[k][m] * Br[m][j];
            }
            Br[k][j] = s_r * pir - s_i * pii;
            Bi[k][j] = s_r * pii + s_i * pir;
        }
    }

    float trr = EPS5, tri = 0.f;
#pragma unroll
    for (int i = 0; i < 8; i++) { trr += Br[i][i]; tri += Bi[i][i]; }
    float tinv = 1.0f / (trr * trr + tri * tri);

    float* wo = wout + (size_t)idx * 16;
#pragma unroll
    for (int i = 0; i < 8; i++) {
        float nr = 0.f, ni = 0.f;
#pragma unroll
        for (int c = 0; c < 8; c++) {
            float uc = u[n * 8 + c];
            nr += Br[i][c] * uc;
            ni += Bi[i][c] * uc;
        }
        float wr = (nr * trr + ni * tri) * tinv;
        float wi = (ni * trr - nr * tri) * tinv;
        wo[i * 2] = wr;        // store conj(w): real
        wo[i * 2 + 1] = -wi;   // store conj(w): imag
    }
}

__global__ __launch_bounds__(256) void beam_kernel(const float* __restrict__ xr,
                                                   const float* __restrict__ xi,
                                                   const float* __restrict__ wc,
                                                   float* __restrict__ out) {
    const int n = blockIdx.z;
    const int f0 = blockIdx.y * 32;
    const int t0 = blockIdx.x * 64;
    const int tid = threadIdx.x;

    __shared__ float wlds[32][16];
    __shared__ float bldr[32][65];
    __shared__ float bldi[32][65];

    for (int s = tid; s < 32 * 16; s += 256) {
        int fl = s >> 4, rest = s & 15;
        int f = f0 + fl;
        wlds[fl][rest] = (f < FF) ? wc[(size_t)(n * FF + f) * 16 + rest] : 0.f;
    }
    __syncthreads();

    const int lane_t = tid & 63, row = tid >> 6;
    const int t = t0 + lane_t;
    const bool tok = t < TT;
    const size_t cstride = (size_t)FF * TT;

#pragma unroll
    for (int k = 0; k < 8; k++) {
        int fl = row + k * 4;
        int f = f0 + fl;
        float br = 0.f, bi = 0.f;
        if (f < FF && tok) {
            size_t base = ((size_t)(n * CCH) * FF + f) * TT + t;
#pragma unroll
            for (int c = 0; c < 8; c++) {
                float vr = xr[base + c * cstride];
                float vi = xi[base + c * cstride];
                float wr = wlds[fl][c * 2], wi_ = wlds[fl][c * 2 + 1];
                br += wr * vr - wi_ * vi;
                bi += wr * vi + wi_ * vr;
            }
        }
        bldr[fl][lane_t] = br;
        bldi[fl][lane_t] = bi;
    }
    __syncthreads();

    const int fc = tid & 31, trb = tid >> 5;
    const int f = f0 + fc;
    float2* outv = (float2*)out;
#pragma unroll
    for (int k = 0; k < 8; k++) {
        int tr = trb + k * 8;
        int t2 = t0 + tr;
        if (f < FF && t2 < TT) {
            float2 v = make_float2(bldr[fc][tr], bldi[fc][tr]);
            outv[(size_t)(n * TT + t2) * FF + f] = v;
        }
    }
}

extern "C" void kernel_launch(void* const* d_in, const int* in_sizes, int n_in,
                              void* d_out, int out_size, void* d_ws, size_t ws_size,
                              hipStream_t stream) {
    const float* mask = (const float*)d_in[0];
    const float* xr = (const float*)d_in[1];
    const float* xi = (const float*)d_in[2];
    const float* pw = (const float*)d_in[3];
    const float* pb = (const float*)d_in[4];
    const float* gw = (const float*)d_in[5];
    const float* gb = (const float*)d_in[6];
    float* out = (float*)d_out;
    float* ws = (float*)d_ws;

    float* cov = ws;                                             // 2056*132
    float* gpart = cov + (size_t)NB * FF * REC_STRIDE;           // 512
    float* u = gpart + 512;                                      // 64
    float* wv = u + 64;                                          // 2056*16

    // atomics accumulate into cov -> zero it every launch (graph-capture-safe)
    hipMemsetAsync(cov, 0, (size_t)NB * FF * REC_STRIDE * sizeof(float), stream);

    hipLaunchKernelGGL(cov_part_kernel, dim3(4, FF, NB * NCH), dim3(64), 0, stream, mask, xr, xi, cov);
    hipLaunchKernelGGL(attn_kernel, dim3(8, NB), dim3(256), 0, stream, cov, pw, pb, gw, gpart);
    hipLaunchKernelGGL(attn2_kernel, dim3(NB), dim3(64), 0, stream, gpart, gb, u);
    hipLaunchKernelGGL(solve_kernel, dim3((NB * FF + 63) / 64), dim3(64), 0, stream, cov, u, wv);
    hipLaunchKernelGGL(beam_kernel, dim3((TT + 63) / 64, (FF + 31) / 32, NB), dim3(256), 0, stream, xr, xi, wv, out);
}